// Round 2
// baseline (19783.337 us; speedup 1.0000x reference)
//
#include <hip/hip_runtime.h>
#include <cmath>

#define TOK 4608      // B*N
#define DMODEL 768

__device__ __forceinline__ float gelu_exact(float x) {
    return 0.5f * x * (1.0f + erff(x * 0.70710678118654752440f));
}

// ---------------- patch embed: tok[b*576+n][d] ----------------
__global__ __launch_bounds__(256)
void patch_embed_kernel(const float* __restrict__ x, const float* __restrict__ pw,
                        const float* __restrict__ pb, const float* __restrict__ pos,
                        float* __restrict__ tok)
{
    int tokid = blockIdx.x;          // b*576 + n
    int b = tokid / 576, n = tokid % 576;
    int hp = n / 24, wp = n % 24;
    int t = threadIdx.x;
    __shared__ float patch[256];
    int ph = t >> 4, pwx = t & 15;
    patch[t] = x[(size_t)b*147456 + (size_t)(hp*16+ph)*384 + (wp*16+pwx)];
    __syncthreads();
    #pragma unroll
    for (int rep = 0; rep < 3; ++rep) {
        int d = t + rep*256;
        const float* wrow = pw + (size_t)d*256;
        float s = 0.f;
        for (int k = 0; k < 256; k += 4) {
            s = fmaf(patch[k],   wrow[k],   s);
            s = fmaf(patch[k+1], wrow[k+1], s);
            s = fmaf(patch[k+2], wrow[k+2], s);
            s = fmaf(patch[k+3], wrow[k+3], s);
        }
        tok[(size_t)tokid*768 + d] = s + pb[d] + pos[(size_t)n*768 + d];
    }
}

// ---------------- LayerNorm over D=768, one block per token ----------------
__global__ __launch_bounds__(256)
void ln_kernel(const float* __restrict__ in, float* __restrict__ out,
               const float* __restrict__ g, const float* __restrict__ bta)
{
    int tokid = blockIdx.x;
    const float* xr = in + (size_t)tokid*768;
    int t = threadIdx.x;
    float v0 = xr[t], v1 = xr[t+256], v2 = xr[t+512];
    float s = v0+v1+v2, q = v0*v0+v1*v1+v2*v2;
    for (int off = 32; off > 0; off >>= 1) {
        s += __shfl_down(s, off);
        q += __shfl_down(q, off);
    }
    __shared__ float ss[4], sq[4];
    int wv = t >> 6, ln = t & 63;
    if (ln == 0) { ss[wv] = s; sq[wv] = q; }
    __syncthreads();
    float ts = ss[0]+ss[1]+ss[2]+ss[3];
    float tq = sq[0]+sq[1]+sq[2]+sq[3];
    float mean = ts * (1.f/768.f);
    float var  = tq * (1.f/768.f) - mean*mean;
    float inv  = rsqrtf(var + 1e-5f);
    float* orow = out + (size_t)tokid*768;
    orow[t]     = (v0-mean)*inv*g[t]     + bta[t];
    orow[t+256] = (v1-mean)*inv*g[t+256] + bta[t+256];
    orow[t+512] = (v2-mean)*inv*g[t+512] + bta[t+512];
}

// ---------------- tiled NT GEMM: C[m,n] = sum_k A[row(m),k]*Bw[n,k] (+bias) --------
// mode 0: C = val       mode 1: C += val (residual)
// mode 2: C[gather] = gelu(val)   mode 3: C[gather] += wgt*val
// 128x128 tile, 8x8 microtile (split quadrants at +64), BK=16,
// register prefetch of next K-tile issued before compute.
// LDS [16][132]: staging writes 2-way, frag reads <=2-way (free).
__global__ __launch_bounds__(256)
void gemm_nt(const float* __restrict__ A, const float* __restrict__ Bw,
             const float* __restrict__ bias, float* __restrict__ C,
             int M, int Nout, int K, int ldA, int ldC, int mode,
             const int* __restrict__ lists, const int* __restrict__ counts,
             const float* __restrict__ wgt)
{
    int Meff = M;
    const int* gather = nullptr;
    if (counts) {
        int e = blockIdx.z;
        Meff   = counts[e];
        gather = lists + e * TOK;
        Bw    += (size_t)e * Nout * K;
        bias  += (size_t)e * Nout;
    }
    int m0 = blockIdx.y << 7, n0 = blockIdx.x << 7;
    if (m0 >= Meff) return;

    __shared__ float As[16][132];
    __shared__ float Bs[16][132];
    int t  = threadIdx.x;
    int lm = t >> 1;                 // staging row-in-tile 0..127
    int lk = (t & 1) << 3;           // staging k-offset 0 or 8
    int tx = t & 15, ty = t >> 4;    // compute: 16x16 threads

    int ar = m0 + lm;
    long agrow = -1;
    if (ar < Meff) agrow = gather ? gather[ar] : ar;
    const float* Arow = (agrow >= 0) ? (A + (size_t)agrow*ldA + lk) : nullptr;
    const float* Brow = Bw + (size_t)(n0 + lm)*K + lk;

    float acc[8][8] = {};
    // prologue: prefetch k0 = 0
    float4 a0 = make_float4(0.f,0.f,0.f,0.f), a1 = a0;
    if (Arow) { a0 = *(const float4*)(Arow); a1 = *(const float4*)(Arow + 4); }
    float4 b0 = *(const float4*)(Brow), b1 = *(const float4*)(Brow + 4);

    for (int k0 = 0; k0 < K; k0 += 16) {
        __syncthreads();   // previous compute done reading LDS
        As[lk+0][lm]=a0.x; As[lk+1][lm]=a0.y; As[lk+2][lm]=a0.z; As[lk+3][lm]=a0.w;
        As[lk+4][lm]=a1.x; As[lk+5][lm]=a1.y; As[lk+6][lm]=a1.z; As[lk+7][lm]=a1.w;
        Bs[lk+0][lm]=b0.x; Bs[lk+1][lm]=b0.y; Bs[lk+2][lm]=b0.z; Bs[lk+3][lm]=b0.w;
        Bs[lk+4][lm]=b1.x; Bs[lk+5][lm]=b1.y; Bs[lk+6][lm]=b1.z; Bs[lk+7][lm]=b1.w;
        __syncthreads();
        // prefetch next tile (latency hides under compute)
        int kn = k0 + 16;
        if (kn < K) {
            if (Arow) { a0 = *(const float4*)(Arow + kn); a1 = *(const float4*)(Arow + kn + 4); }
            b0 = *(const float4*)(Brow + kn); b1 = *(const float4*)(Brow + kn + 4);
        }
        #pragma unroll
        for (int kk = 0; kk < 16; ++kk) {
            float af[8], bf[8];
            *(float4*)(af)   = *(const float4*)&As[kk][ty<<2];
            *(float4*)(af+4) = *(const float4*)&As[kk][64 + (ty<<2)];
            *(float4*)(bf)   = *(const float4*)&Bs[kk][tx<<2];
            *(float4*)(bf+4) = *(const float4*)&Bs[kk][64 + (tx<<2)];
            #pragma unroll
            for (int i = 0; i < 8; ++i)
                #pragma unroll
                for (int j = 0; j < 8; ++j)
                    acc[i][j] = fmaf(af[i], bf[j], acc[i][j]);
        }
    }

    #pragma unroll
    for (int ih = 0; ih < 2; ++ih) {
        #pragma unroll
        for (int i = 0; i < 4; ++i) {
            int m = m0 + ih*64 + (ty<<2) + i;
            if (m >= Meff) continue;
            int row = gather ? gather[m] : m;
            #pragma unroll
            for (int jh = 0; jh < 2; ++jh) {
                int n = n0 + jh*64 + (tx<<2);
                float4 bi = *(const float4*)&bias[n];
                float v0 = acc[ih*4+i][jh*4+0] + bi.x;
                float v1 = acc[ih*4+i][jh*4+1] + bi.y;
                float v2 = acc[ih*4+i][jh*4+2] + bi.z;
                float v3 = acc[ih*4+i][jh*4+3] + bi.w;
                float* cp = C + (size_t)row*ldC + n;
                if (mode == 0) {
                    *(float4*)cp = make_float4(v0, v1, v2, v3);
                } else if (mode == 1) {
                    float4 c = *(const float4*)cp;
                    *(float4*)cp = make_float4(c.x+v0, c.y+v1, c.z+v2, c.w+v3);
                } else if (mode == 2) {
                    *(float4*)cp = make_float4(gelu_exact(v0), gelu_exact(v1),
                                               gelu_exact(v2), gelu_exact(v3));
                } else {
                    float w = wgt[row];
                    float4 c = *(const float4*)cp;
                    *(float4*)cp = make_float4(c.x + w*v0, c.y + w*v1,
                                               c.z + w*v2, c.w + w*v3);
                }
            }
        }
    }
}

// ---------------- attention: one block = (16 q-rows, head, batch) ----------------
__global__ __launch_bounds__(256)
void attn_kernel(const float* __restrict__ qkv, float* __restrict__ attn)
{
    int q0 = blockIdx.x << 4;
    int h  = blockIdx.y;
    int b  = blockIdx.z;
    const float* base = qkv + (size_t)b * 576 * 2304;
    int qoff = h << 6, koff = 768 + (h<<6), voff = 1536 + (h<<6);
    __shared__ float qs[16][68], kt[16][68];
    __shared__ float sc[16][592];
    __shared__ float ssum[16];
    int t = threadIdx.x;
    int r = t >> 4, c4 = (t & 15) << 2;
    *(float4*)&qs[r][c4] = *(const float4*)&base[(size_t)(q0 + r)*2304 + qoff + c4];
    __syncthreads();
    int jj = t & 15;
    for (int j0 = 0; j0 < 576; j0 += 16) {
        *(float4*)&kt[r][c4] = *(const float4*)&base[(size_t)(j0 + r)*2304 + koff + c4];
        __syncthreads();
        float s = 0.f;
        #pragma unroll
        for (int d = 0; d < 64; d += 4) {
            float qa[4], ka[4];
            *(float4*)qa = *(const float4*)&qs[r][d];
            *(float4*)ka = *(const float4*)&kt[jj][d];
            s = fmaf(qa[0],ka[0], fmaf(qa[1],ka[1], fmaf(qa[2],ka[2], fmaf(qa[3],ka[3], s))));
        }
        sc[r][j0 + jj] = s * 0.125f;
        __syncthreads();
    }
    // softmax per row: 16 threads per row (same wave), keep un-normalized exp + sum
    {
        int row = t >> 4, l16 = t & 15;
        float mx = -3.4e38f;
        for (int j = l16; j < 576; j += 16) mx = fmaxf(mx, sc[row][j]);
        #pragma unroll
        for (int off = 8; off > 0; off >>= 1) mx = fmaxf(mx, __shfl_xor(mx, off, 16));
        float sum = 0.f;
        for (int j = l16; j < 576; j += 16) {
            float e = expf(sc[row][j] - mx);
            sc[row][j] = e;
            sum += e;
        }
        #pragma unroll
        for (int off = 8; off > 0; off >>= 1) sum += __shfl_xor(sum, off, 16);
        if (l16 == 0) ssum[row] = sum;
    }
    __syncthreads();
    // PV: thread handles (d = t&63, rows rb..rb+3); V staged through LDS (kt reused)
    int d = t & 63, rb = (t >> 6) << 2;
    float acc[4] = {0.f,0.f,0.f,0.f};
    for (int j0 = 0; j0 < 576; j0 += 16) {
        *(float4*)&kt[r][c4] = *(const float4*)&base[(size_t)(j0 + r)*2304 + voff + c4];
        __syncthreads();
        #pragma unroll
        for (int jj4 = 0; jj4 < 16; jj4 += 4) {
            float a0[4], a1[4], a2[4], a3[4];
            *(float4*)a0 = *(const float4*)&sc[rb+0][j0+jj4];
            *(float4*)a1 = *(const float4*)&sc[rb+1][j0+jj4];
            *(float4*)a2 = *(const float4*)&sc[rb+2][j0+jj4];
            *(float4*)a3 = *(const float4*)&sc[rb+3][j0+jj4];
            #pragma unroll
            for (int u = 0; u < 4; ++u) {
                float v = kt[jj4+u][d];
                acc[0] = fmaf(a0[u], v, acc[0]);
                acc[1] = fmaf(a1[u], v, acc[1]);
                acc[2] = fmaf(a2[u], v, acc[2]);
                acc[3] = fmaf(a3[u], v, acc[3]);
            }
        }
        __syncthreads();
    }
    #pragma unroll
    for (int i = 0; i < 4; ++i)
        attn[(size_t)(b*576 + q0 + rb + i)*768 + qoff + d] = acc[i] / ssum[rb+i];
}

// ---------------- gate: scores -> argmax -> expert lists ----------------
__global__ __launch_bounds__(256)
void gate_kernel(const float* __restrict__ h2, const float* __restrict__ gw,
                 const float* __restrict__ gb, float* __restrict__ wgt,
                 int* __restrict__ lists, int* __restrict__ counts)
{
    int tokid = blockIdx.x;
    int t = threadIdx.x;
    const float* hr = h2 + (size_t)tokid*768;
    float p0=0.f,p1=0.f,p2=0.f,p3=0.f;
    for (int k = t; k < 768; k += 256) {
        float hv = hr[k];
        p0 = fmaf(hv, gw[k],        p0);
        p1 = fmaf(hv, gw[768 + k],  p1);
        p2 = fmaf(hv, gw[1536 + k], p2);
        p3 = fmaf(hv, gw[2304 + k], p3);
    }
    for (int off = 32; off > 0; off >>= 1) {
        p0 += __shfl_down(p0, off);
        p1 += __shfl_down(p1, off);
        p2 += __shfl_down(p2, off);
        p3 += __shfl_down(p3, off);
    }
    __shared__ float red[4][4];
    int wv = t >> 6, ln = t & 63;
    if (ln == 0) { red[wv][0]=p0; red[wv][1]=p1; red[wv][2]=p2; red[wv][3]=p3; }
    __syncthreads();
    if (t == 0) {
        float s[4];
        #pragma unroll
        for (int e = 0; e < 4; ++e)
            s[e] = red[0][e]+red[1][e]+red[2][e]+red[3][e] + gb[e];
        int best = 0; float bv = s[0];
        #pragma unroll
        for (int e = 1; e < 4; ++e) if (s[e] > bv) { bv = s[e]; best = e; }  // first-max tie-break
        wgt[tokid] = bv;
        int pos = atomicAdd(&counts[best], 1);
        lists[best*TOK + pos] = tokid;
    }
}

__global__ void zero_counts(int* counts) { if (threadIdx.x < 4) counts[threadIdx.x] = 0; }

// ---------------- final b (h w) c -> b c h w ----------------
__global__ __launch_bounds__(256)
void out_transpose(const float* __restrict__ tok, float* __restrict__ out)
{
    int idx = blockIdx.x*256 + threadIdx.x;   // ((b*768+d)*24+hp)*24+wp
    int wp = idx % 24;
    int hp = (idx / 24) % 24;
    int d  = (idx / 576) % 768;
    int b  = idx / (576*768);
    out[idx] = tok[(size_t)(b*576 + hp*24 + wp)*768 + d];
}

extern "C" void kernel_launch(void* const* d_in, const int* in_sizes, int n_in,
                              void* d_out, int out_size, void* d_ws, size_t ws_size,
                              hipStream_t stream)
{
    const float* x       = (const float*)d_in[0];
    const float* patch_w = (const float*)d_in[1];
    const float* patch_b = (const float*)d_in[2];
    const float* pos     = (const float*)d_in[3];
    const float* ln1_g   = (const float*)d_in[4];
    const float* ln1_b   = (const float*)d_in[5];
    const float* qkv_w   = (const float*)d_in[6];
    const float* qkv_b   = (const float*)d_in[7];
    const float* out_w   = (const float*)d_in[8];
    const float* out_b   = (const float*)d_in[9];
    const float* ln2_g   = (const float*)d_in[10];
    const float* ln2_b   = (const float*)d_in[11];
    const float* gate_w  = (const float*)d_in[12];
    const float* gate_b  = (const float*)d_in[13];
    const float* w1      = (const float*)d_in[14];
    const float* b1      = (const float*)d_in[15];
    const float* w2      = (const float*)d_in[16];
    const float* b2      = (const float*)d_in[17];
    float* out = (float*)d_out;

    // workspace layout (floats): tok | h | scratch{qkv,attn} (hid aliases scratch) | wgt | lists | counts
    float* ws    = (float*)d_ws;
    float* tok   = ws;                       // 3,538,944
    float* h     = ws + 3538944;             // 3,538,944
    float* scr   = ws + 7077888;             // 14,155,776 (qkv 10,616,832 + attn 3,538,944)
    float* qkv   = scr;
    float* attn  = scr + 10616832;
    float* hid   = scr;                      // aliases qkv+attn (dead by FFN time)
    float* wgt   = ws + 21233664;            // 4608
    int*   lists = (int*)(ws + 21238272);    // 4*4608
    int*   counts= (int*)(ws + 21256704);    // 4

    patch_embed_kernel<<<4608, 256, 0, stream>>>(x, patch_w, patch_b, pos, tok);

    for (int l = 0; l < 12; ++l) {
        ln_kernel<<<4608, 256, 0, stream>>>(tok, h, ln1_g + l*768, ln1_b + l*768);
        gemm_nt<<<dim3(18,36,1), 256, 0, stream>>>(h, qkv_w + (size_t)l*2304*768, qkv_b + l*2304,
                                                   qkv, 4608, 2304, 768, 768, 2304, 0,
                                                   nullptr, nullptr, nullptr);
        attn_kernel<<<dim3(36,12,8), 256, 0, stream>>>(qkv, attn);
        gemm_nt<<<dim3(6,36,1), 256, 0, stream>>>(attn, out_w + (size_t)l*768*768, out_b + l*768,
                                                  tok, 4608, 768, 768, 768, 768, 1,
                                                  nullptr, nullptr, nullptr);
        ln_kernel<<<4608, 256, 0, stream>>>(tok, h, ln2_g + l*768, ln2_b + l*768);
        zero_counts<<<1, 64, 0, stream>>>(counts);
        gate_kernel<<<4608, 256, 0, stream>>>(h, gate_w + l*3072, gate_b + l*4, wgt, lists, counts);
        gemm_nt<<<dim3(24,36,4), 256, 0, stream>>>(h, w1 + (size_t)l*4*3072*768, b1 + (size_t)l*4*3072,
                                                   hid, 4608, 3072, 768, 768, 3072, 2,
                                                   lists, counts, nullptr);
        gemm_nt<<<dim3(6,36,4), 256, 0, stream>>>(hid, w2 + (size_t)l*4*768*3072, b2 + (size_t)l*4*768,
                                                  tok, 4608, 768, 3072, 3072, 768, 3,
                                                  lists, counts, wgt);
    }
    out_transpose<<<13824, 256, 0, stream>>>(tok, out);
}

// Round 4
// 14243.498 us; speedup vs baseline: 1.3889x; 1.3889x over previous
//
#include <hip/hip_runtime.h>
#include <cmath>

#define TOK 4608      // B*N
#define DMODEL 768

typedef __attribute__((ext_vector_type(8))) short bf16x8;
typedef __attribute__((ext_vector_type(4))) float f32x4;

__device__ __forceinline__ float gelu_exact(float x) {
    return 0.5f * x * (1.0f + erff(x * 0.70710678118654752440f));
}

// 3-limb bf16 decomposition, round-to-nearest-even for h and m, truncate l.
// x = h + m + l + delta, |delta| <= 2^-23 |x|. Residuals r1, r2 are exact in fp32.
__device__ __forceinline__ void cvt3(float x, unsigned short& h, unsigned short& m,
                                     unsigned short& l)
{
    unsigned u  = __float_as_uint(x);
    unsigned hb = (u + 0x7FFFu + ((u >> 16) & 1u)) & 0xFFFF0000u;
    float    r1 = x - __uint_as_float(hb);
    unsigned u1 = __float_as_uint(r1);
    unsigned mb = (u1 + 0x7FFFu + ((u1 >> 16) & 1u)) & 0xFFFF0000u;
    float    r2 = r1 - __uint_as_float(mb);
    h = (unsigned short)(hb >> 16);
    m = (unsigned short)(mb >> 16);
    l = (unsigned short)(__float_as_uint(r2) >> 16);
}

__device__ __forceinline__ void cvt3_pack8(const float4 a, const float4 b,
                                           uint4& H, uint4& M, uint4& L)
{
    unsigned short h[8], m[8], l[8];
    cvt3(a.x, h[0], m[0], l[0]); cvt3(a.y, h[1], m[1], l[1]);
    cvt3(a.z, h[2], m[2], l[2]); cvt3(a.w, h[3], m[3], l[3]);
    cvt3(b.x, h[4], m[4], l[4]); cvt3(b.y, h[5], m[5], l[5]);
    cvt3(b.z, h[6], m[6], l[6]); cvt3(b.w, h[7], m[7], l[7]);
    H = (uint4){ (unsigned)h[0] | ((unsigned)h[1] << 16), (unsigned)h[2] | ((unsigned)h[3] << 16),
                 (unsigned)h[4] | ((unsigned)h[5] << 16), (unsigned)h[6] | ((unsigned)h[7] << 16) };
    M = (uint4){ (unsigned)m[0] | ((unsigned)m[1] << 16), (unsigned)m[2] | ((unsigned)m[3] << 16),
                 (unsigned)m[4] | ((unsigned)m[5] << 16), (unsigned)m[6] | ((unsigned)m[7] << 16) };
    L = (uint4){ (unsigned)l[0] | ((unsigned)l[1] << 16), (unsigned)l[2] | ((unsigned)l[3] << 16),
                 (unsigned)l[4] | ((unsigned)l[5] << 16), (unsigned)l[6] | ((unsigned)l[7] << 16) };
}

// ---------------- patch embed: tok[b*576+n][d] ----------------
__global__ __launch_bounds__(256)
void patch_embed_kernel(const float* __restrict__ x, const float* __restrict__ pw,
                        const float* __restrict__ pb, const float* __restrict__ pos,
                        float* __restrict__ tok)
{
    int tokid = blockIdx.x;          // b*576 + n
    int b = tokid / 576, n = tokid % 576;
    int hp = n / 24, wp = n % 24;
    int t = threadIdx.x;
    __shared__ float patch[256];
    int ph = t >> 4, pwx = t & 15;
    patch[t] = x[(size_t)b*147456 + (size_t)(hp*16+ph)*384 + (wp*16+pwx)];
    __syncthreads();
    #pragma unroll
    for (int rep = 0; rep < 3; ++rep) {
        int d = t + rep*256;
        const float* wrow = pw + (size_t)d*256;
        float s = 0.f;
        for (int k = 0; k < 256; k += 4) {
            s = fmaf(patch[k],   wrow[k],   s);
            s = fmaf(patch[k+1], wrow[k+1], s);
            s = fmaf(patch[k+2], wrow[k+2], s);
            s = fmaf(patch[k+3], wrow[k+3], s);
        }
        tok[(size_t)tokid*768 + d] = s + pb[d] + pos[(size_t)n*768 + d];
    }
}

// ---------------- LayerNorm over D=768, one block per token ----------------
__global__ __launch_bounds__(256)
void ln_kernel(const float* __restrict__ in, float* __restrict__ out,
               const float* __restrict__ g, const float* __restrict__ bta)
{
    int tokid = blockIdx.x;
    const float* xr = in + (size_t)tokid*768;
    int t = threadIdx.x;
    float v0 = xr[t], v1 = xr[t+256], v2 = xr[t+512];
    float s = v0+v1+v2, q = v0*v0+v1*v1+v2*v2;
    for (int off = 32; off > 0; off >>= 1) {
        s += __shfl_down(s, off);
        q += __shfl_down(q, off);
    }
    __shared__ float ss[4], sq[4];
    int wv = t >> 6, ln = t & 63;
    if (ln == 0) { ss[wv] = s; sq[wv] = q; }
    __syncthreads();
    float ts = ss[0]+ss[1]+ss[2]+ss[3];
    float tq = sq[0]+sq[1]+sq[2]+sq[3];
    float mean = ts * (1.f/768.f);
    float var  = tq * (1.f/768.f) - mean*mean;
    float inv  = rsqrtf(var + 1e-5f);
    float* orow = out + (size_t)tokid*768;
    orow[t]     = (v0-mean)*inv*g[t]     + bta[t];
    orow[t+256] = (v1-mean)*inv*g[t+256] + bta[t+256];
    orow[t+512] = (v2-mean)*inv*g[t+512] + bta[t+512];
}

// ---------------- MFMA NT GEMM: C[row(m),n] = sum_k A[row(m),k]*Bw[n,k] (+bias) ----
// 3-limb bf16 split (h,m,l RN), 6 MFMA terms: hh, hm, mh, mm, hl, lh.
// Dropped terms ~6*2^-24 relative -> fp32-class accuracy (at/below fp32 reorder noise).
// 128x128 tile, BK=32, 4 waves (2x2), each wave 64x64 = 4x4 frags of 16x16x32.
// LDS 6x[128][40] ushort (row stride 80B): frag reads & staging writes <=2-way (free).
// mode 0: C = val   1: C += val   2: C[gather] = gelu(val)   3: C[gather] += wgt*val
__global__ __launch_bounds__(256, 2)
void gemm_mfma(const float* __restrict__ A, const float* __restrict__ Bw,
               const float* __restrict__ bias, float* __restrict__ C,
               int M, int Nout, int K, int ldA, int ldC, int mode,
               const int* __restrict__ lists, const int* __restrict__ counts,
               const float* __restrict__ wgt)
{
    int Meff = M;
    const int* gather = nullptr;
    if (counts) {
        int e = blockIdx.z;
        Meff   = counts[e];
        gather = lists + e * TOK;
        Bw    += (size_t)e * Nout * K;
        bias  += (size_t)e * Nout;
    }
    int m0 = blockIdx.y << 7, n0 = blockIdx.x << 7;
    if (m0 >= Meff) return;

    __shared__ unsigned short Ah[128][40];
    __shared__ unsigned short Am[128][40];
    __shared__ unsigned short Al[128][40];
    __shared__ unsigned short Bh[128][40];
    __shared__ unsigned short Bm[128][40];
    __shared__ unsigned short Bl[128][40];

    int t = threadIdx.x;
    // staging: thread t covers row (t>>1), k-half (t&1)*16 (16 floats)
    int srow = t >> 1;
    int koff = (t & 1) << 4;

    int ar = m0 + srow;
    long agrow = -1;
    if (ar < Meff) agrow = gather ? gather[ar] : ar;
    const float* Asrc = (agrow >= 0) ? (A + (size_t)agrow*ldA + koff) : nullptr;
    const float* Bsrc = Bw + (size_t)(n0 + srow)*K + koff;

    // compute mapping: wave (2x2), lane -> fragment coords
    int lane = t & 63;
    int wv   = t >> 6;
    int wm   = (wv >> 1) << 6;   // 0 / 64
    int wn   = (wv & 1) << 6;    // 0 / 64
    int r16  = lane & 15;
    int g    = lane >> 4;        // k-group 0..3 (8 k each)

    f32x4 acc[4][4];
    #pragma unroll
    for (int i = 0; i < 4; ++i)
        #pragma unroll
        for (int j = 0; j < 4; ++j)
            acc[i][j] = (f32x4){0.f, 0.f, 0.f, 0.f};

    float4 ra[4], rb[4];
    ra[0] = ra[1] = ra[2] = ra[3] = make_float4(0.f, 0.f, 0.f, 0.f);

    auto load_tile = [&](int k0) {
        if (Asrc) {
            ra[0] = *(const float4*)(Asrc + k0);
            ra[1] = *(const float4*)(Asrc + k0 + 4);
            ra[2] = *(const float4*)(Asrc + k0 + 8);
            ra[3] = *(const float4*)(Asrc + k0 + 12);
        }
        rb[0] = *(const float4*)(Bsrc + k0);
        rb[1] = *(const float4*)(Bsrc + k0 + 4);
        rb[2] = *(const float4*)(Bsrc + k0 + 8);
        rb[3] = *(const float4*)(Bsrc + k0 + 12);
    };

    auto stage = [&]() {
        uint4 H, M_, L;
        cvt3_pack8(ra[0], ra[1], H, M_, L);
        *(uint4*)&Ah[srow][koff]     = H;
        *(uint4*)&Am[srow][koff]     = M_;
        *(uint4*)&Al[srow][koff]     = L;
        cvt3_pack8(ra[2], ra[3], H, M_, L);
        *(uint4*)&Ah[srow][koff + 8] = H;
        *(uint4*)&Am[srow][koff + 8] = M_;
        *(uint4*)&Al[srow][koff + 8] = L;
        cvt3_pack8(rb[0], rb[1], H, M_, L);
        *(uint4*)&Bh[srow][koff]     = H;
        *(uint4*)&Bm[srow][koff]     = M_;
        *(uint4*)&Bl[srow][koff]     = L;
        cvt3_pack8(rb[2], rb[3], H, M_, L);
        *(uint4*)&Bh[srow][koff + 8] = H;
        *(uint4*)&Bm[srow][koff + 8] = M_;
        *(uint4*)&Bl[srow][koff + 8] = L;
    };

    load_tile(0);

    for (int k0 = 0; k0 < K; k0 += 32) {
        __syncthreads();          // previous compute done reading LDS
        stage();
        __syncthreads();
        if (k0 + 32 < K) load_tile(k0 + 32);   // prefetch hides under MFMA

        bf16x8 fah[4], fam[4], fal[4];
        #pragma unroll
        for (int i = 0; i < 4; ++i) {
            int ml = wm + i*16 + r16;
            fah[i] = *(const bf16x8*)&Ah[ml][g*8];
            fam[i] = *(const bf16x8*)&Am[ml][g*8];
            fal[i] = *(const bf16x8*)&Al[ml][g*8];
        }
        #pragma unroll
        for (int j = 0; j < 4; ++j) {
            int nl = wn + j*16 + r16;
            bf16x8 fbh = *(const bf16x8*)&Bh[nl][g*8];
            bf16x8 fbm = *(const bf16x8*)&Bm[nl][g*8];
            bf16x8 fbl = *(const bf16x8*)&Bl[nl][g*8];
            #pragma unroll
            for (int i = 0; i < 4; ++i) {
                acc[i][j] = __builtin_amdgcn_mfma_f32_16x16x32_bf16(fah[i], fbh, acc[i][j], 0, 0, 0);
                acc[i][j] = __builtin_amdgcn_mfma_f32_16x16x32_bf16(fam[i], fbh, acc[i][j], 0, 0, 0);
                acc[i][j] = __builtin_amdgcn_mfma_f32_16x16x32_bf16(fah[i], fbm, acc[i][j], 0, 0, 0);
                acc[i][j] = __builtin_amdgcn_mfma_f32_16x16x32_bf16(fam[i], fbm, acc[i][j], 0, 0, 0);
                acc[i][j] = __builtin_amdgcn_mfma_f32_16x16x32_bf16(fal[i], fbh, acc[i][j], 0, 0, 0);
                acc[i][j] = __builtin_amdgcn_mfma_f32_16x16x32_bf16(fah[i], fbl, acc[i][j], 0, 0, 0);
            }
        }
    }

    // epilogue: lane holds D[(g*4+r)][r16] of each 16x16 frag
    float biasv[4];
    #pragma unroll
    for (int j = 0; j < 4; ++j) biasv[j] = bias[n0 + wn + j*16 + r16];

    #pragma unroll
    for (int i = 0; i < 4; ++i) {
        int mb = m0 + wm + i*16 + (g << 2);
        #pragma unroll
        for (int r = 0; r < 4; ++r) {
            int m = mb + r;
            if (m >= Meff) continue;
            int row = gather ? gather[m] : m;
            float* crow = C + (size_t)row*ldC + n0 + wn + r16;
            float w = (mode == 3) ? wgt[row] : 0.f;
            #pragma unroll
            for (int j = 0; j < 4; ++j) {
                float val = acc[i][j][r] + biasv[j];
                float* cp = crow + j*16;
                if      (mode == 0) *cp = val;
                else if (mode == 1) *cp += val;
                else if (mode == 2) *cp = gelu_exact(val);
                else                *cp += w * val;
            }
        }
    }
}

// ---------------- attention: one block = (16 q-rows, head, batch) ----------------
__global__ __launch_bounds__(256)
void attn_kernel(const float* __restrict__ qkv, float* __restrict__ attn)
{
    int q0 = blockIdx.x << 4;
    int h  = blockIdx.y;
    int b  = blockIdx.z;
    const float* base = qkv + (size_t)b * 576 * 2304;
    int qoff = h << 6, koff = 768 + (h<<6), voff = 1536 + (h<<6);
    __shared__ float qs[16][68], kt[16][68];
    __shared__ float sc[16][592];
    __shared__ float ssum[16];
    int t = threadIdx.x;
    int r = t >> 4, c4 = (t & 15) << 2;
    *(float4*)&qs[r][c4] = *(const float4*)&base[(size_t)(q0 + r)*2304 + qoff + c4];
    __syncthreads();
    int jj = t & 15;
    for (int j0 = 0; j0 < 576; j0 += 16) {
        *(float4*)&kt[r][c4] = *(const float4*)&base[(size_t)(j0 + r)*2304 + koff + c4];
        __syncthreads();
        float s = 0.f;
        #pragma unroll
        for (int d = 0; d < 64; d += 4) {
            float qa[4], ka[4];
            *(float4*)qa = *(const float4*)&qs[r][d];
            *(float4*)ka = *(const float4*)&kt[jj][d];
            s = fmaf(qa[0],ka[0], fmaf(qa[1],ka[1], fmaf(qa[2],ka[2], fmaf(qa[3],ka[3], s))));
        }
        sc[r][j0 + jj] = s * 0.125f;
        __syncthreads();
    }
    // softmax per row: 16 threads per row (same wave), keep un-normalized exp + sum
    {
        int row = t >> 4, l16 = t & 15;
        float mx = -3.4e38f;
        for (int j = l16; j < 576; j += 16) mx = fmaxf(mx, sc[row][j]);
        #pragma unroll
        for (int off = 8; off > 0; off >>= 1) mx = fmaxf(mx, __shfl_xor(mx, off, 16));
        float sum = 0.f;
        for (int j = l16; j < 576; j += 16) {
            float e = expf(sc[row][j] - mx);
            sc[row][j] = e;
            sum += e;
        }
        #pragma unroll
        for (int off = 8; off > 0; off >>= 1) sum += __shfl_xor(sum, off, 16);
        if (l16 == 0) ssum[row] = sum;
    }
    __syncthreads();
    // PV: thread handles (d = t&63, rows rb..rb+3); V staged through LDS (kt reused)
    int d = t & 63, rb = (t >> 6) << 2;
    float acc[4] = {0.f,0.f,0.f,0.f};
    for (int j0 = 0; j0 < 576; j0 += 16) {
        *(float4*)&kt[r][c4] = *(const float4*)&base[(size_t)(j0 + r)*2304 + voff + c4];
        __syncthreads();
        #pragma unroll
        for (int jj4 = 0; jj4 < 16; jj4 += 4) {
            float a0[4], a1[4], a2[4], a3[4];
            *(float4*)a0 = *(const float4*)&sc[rb+0][j0+jj4];
            *(float4*)a1 = *(const float4*)&sc[rb+1][j0+jj4];
            *(float4*)a2 = *(const float4*)&sc[rb+2][j0+jj4];
            *(float4*)a3 = *(const float4*)&sc[rb+3][j0+jj4];
            #pragma unroll
            for (int u = 0; u < 4; ++u) {
                float v = kt[jj4+u][d];
                acc[0] = fmaf(a0[u], v, acc[0]);
                acc[1] = fmaf(a1[u], v, acc[1]);
                acc[2] = fmaf(a2[u], v, acc[2]);
                acc[3] = fmaf(a3[u], v, acc[3]);
            }
        }
        __syncthreads();
    }
    #pragma unroll
    for (int i = 0; i < 4; ++i)
        attn[(size_t)(b*576 + q0 + rb + i)*768 + qoff + d] = acc[i] / ssum[rb+i];
}

// ---------------- gate: scores -> argmax -> expert lists ----------------
__global__ __launch_bounds__(256)
void gate_kernel(const float* __restrict__ h2, const float* __restrict__ gw,
                 const float* __restrict__ gb, float* __restrict__ wgt,
                 int* __restrict__ lists, int* __restrict__ counts)
{
    int tokid = blockIdx.x;
    int t = threadIdx.x;
    const float* hr = h2 + (size_t)tokid*768;
    float p0=0.f,p1=0.f,p2=0.f,p3=0.f;
    for (int k = t; k < 768; k += 256) {
        float hv = hr[k];
        p0 = fmaf(hv, gw[k],        p0);
        p1 = fmaf(hv, gw[768 + k],  p1);
        p2 = fmaf(hv, gw[1536 + k], p2);
        p3 = fmaf(hv, gw[2304 + k], p3);
    }
    for (int off = 32; off > 0; off >>= 1) {
        p0 += __shfl_down(p0, off);
        p1 += __shfl_down(p1, off);
        p2 += __shfl_down(p2, off);
        p3 += __shfl_down(p3, off);
    }
    __shared__ float red[4][4];
    int wv = t >> 6, ln = t & 63;
    if (ln == 0) { red[wv][0]=p0; red[wv][1]=p1; red[wv][2]=p2; red[wv][3]=p3; }
    __syncthreads();
    if (t == 0) {
        float s[4];
        #pragma unroll
        for (int e = 0; e < 4; ++e)
            s[e] = red[0][e]+red[1][e]+red[2][e]+red[3][e] + gb[e];
        int best = 0; float bv = s[0];
        #pragma unroll
        for (int e = 1; e < 4; ++e) if (s[e] > bv) { bv = s[e]; best = e; }  // first-max tie-break
        wgt[tokid] = bv;
        int pos = atomicAdd(&counts[best], 1);
        lists[best*TOK + pos] = tokid;
    }
}

__global__ void zero_counts(int* counts) { if (threadIdx.x < 4) counts[threadIdx.x] = 0; }

// ---------------- final b (h w) c -> b c h w ----------------
__global__ __launch_bounds__(256)
void out_transpose(const float* __restrict__ tok, float* __restrict__ out)
{
    int idx = blockIdx.x*256 + threadIdx.x;   // ((b*768+d)*24+hp)*24+wp
    int wp = idx % 24;
    int hp = (idx / 24) % 24;
    int d  = (idx / 576) % 768;
    int b  = idx / (576*768);
    out[idx] = tok[(size_t)(b*576 + hp*24 + wp)*768 + d];
}

extern "C" void kernel_launch(void* const* d_in, const int* in_sizes, int n_in,
                              void* d_out, int out_size, void* d_ws, size_t ws_size,
                              hipStream_t stream)
{
    const float* x       = (const float*)d_in[0];
    const float* patch_w = (const float*)d_in[1];
    const float* patch_b = (const float*)d_in[2];
    const float* pos     = (const float*)d_in[3];
    const float* ln1_g   = (const float*)d_in[4];
    const float* ln1_b   = (const float*)d_in[5];
    const float* qkv_w   = (const float*)d_in[6];
    const float* qkv_b   = (const float*)d_in[7];
    const float* out_w   = (const float*)d_in[8];
    const float* out_b   = (const float*)d_in[9];
    const float* ln2_g   = (const float*)d_in[10];
    const float* ln2_b   = (const float*)d_in[11];
    const float* gate_w  = (const float*)d_in[12];
    const float* gate_b  = (const float*)d_in[13];
    const float* w1      = (const float*)d_in[14];
    const float* b1      = (const float*)d_in[15];
    const float* w2      = (const float*)d_in[16];
    const float* b2      = (const float*)d_in[17];
    float* out = (float*)d_out;

    // workspace layout (floats): tok | h | scratch{qkv,attn} (hid aliases scratch) | wgt | lists | counts
    float* ws    = (float*)d_ws;
    float* tok   = ws;                       // 3,538,944
    float* h     = ws + 3538944;             // 3,538,944
    float* scr   = ws + 7077888;             // 14,155,776 (qkv 10,616,832 + attn 3,538,944)
    float* qkv   = scr;
    float* attn  = scr + 10616832;
    float* hid   = scr;                      // aliases qkv+attn (dead by FFN time)
    float* wgt   = ws + 21233664;            // 4608
    int*   lists = (int*)(ws + 21238272);    // 4*4608
    int*   counts= (int*)(ws + 21256704);    // 4

    patch_embed_kernel<<<4608, 256, 0, stream>>>(x, patch_w, patch_b, pos, tok);

    for (int l = 0; l < 12; ++l) {
        ln_kernel<<<4608, 256, 0, stream>>>(tok, h, ln1_g + l*768, ln1_b + l*768);
        gemm_mfma<<<dim3(18,36,1), 256, 0, stream>>>(h, qkv_w + (size_t)l*2304*768, qkv_b + l*2304,
                                                     qkv, 4608, 2304, 768, 768, 2304, 0,
                                                     nullptr, nullptr, nullptr);
        attn_kernel<<<dim3(36,12,8), 256, 0, stream>>>(qkv, attn);
        gemm_mfma<<<dim3(6,36,1), 256, 0, stream>>>(attn, out_w + (size_t)l*768*768, out_b + l*768,
                                                    tok, 4608, 768, 768, 768, 768, 1,
                                                    nullptr, nullptr, nullptr);
        ln_kernel<<<4608, 256, 0, stream>>>(tok, h, ln2_g + l*768, ln2_b + l*768);
        zero_counts<<<1, 64, 0, stream>>>(counts);
        gate_kernel<<<4608, 256, 0, stream>>>(h, gate_w + l*3072, gate_b + l*4, wgt, lists, counts);
        gemm_mfma<<<dim3(24,36,4), 256, 0, stream>>>(h, w1 + (size_t)l*4*3072*768, b1 + (size_t)l*4*3072,
                                                     hid, 4608, 3072, 768, 768, 3072, 2,
                                                     lists, counts, nullptr);
        gemm_mfma<<<dim3(6,36,4), 256, 0, stream>>>(hid, w2 + (size_t)l*4*768*3072, b2 + (size_t)l*4*768,
                                                    tok, 4608, 768, 3072, 3072, 768, 3,
                                                    lists, counts, wgt);
    }
    out_transpose<<<13824, 256, 0, stream>>>(tok, out);
}

// Round 5
// 11487.242 us; speedup vs baseline: 1.7222x; 1.2399x over previous
//
#include <hip/hip_runtime.h>
#include <cmath>

#define TOK 4608      // B*N
#define DMODEL 768

typedef __attribute__((ext_vector_type(8))) _Float16 f16x8;
typedef __attribute__((ext_vector_type(4))) float f32x4;

__device__ __forceinline__ float gelu_exact(float x) {
    return 0.5f * x * (1.0f + erff(x * 0.70710678118654752440f));
}

// 2-limb fp16 decomposition, RN both limbs. x = h + m/2048 + delta, |delta| <= 2^-22 |x|.
// m is pre-scaled by 2048 so it is never subnormal (robust to MFMA input-denorm flush);
// the hm/mh accumulator is scaled back by 1/2048 in the epilogue.
__device__ __forceinline__ void cvt2(float x, unsigned short& h, unsigned short& m)
{
    _Float16 hf = (_Float16)x;                  // v_cvt_f16_f32 (RN)
    float r = (x - (float)hf) * 2048.0f;        // exact residual (Sterbenz), rescaled
    _Float16 mf = (_Float16)r;
    h = __builtin_bit_cast(unsigned short, hf);
    m = __builtin_bit_cast(unsigned short, mf);
}

__device__ __forceinline__ void cvt2_pack8(const float4 a, const float4 b,
                                           uint4& H, uint4& M)
{
    unsigned short h[8], m[8];
    cvt2(a.x, h[0], m[0]); cvt2(a.y, h[1], m[1]);
    cvt2(a.z, h[2], m[2]); cvt2(a.w, h[3], m[3]);
    cvt2(b.x, h[4], m[4]); cvt2(b.y, h[5], m[5]);
    cvt2(b.z, h[6], m[6]); cvt2(b.w, h[7], m[7]);
    H = (uint4){ (unsigned)h[0] | ((unsigned)h[1] << 16), (unsigned)h[2] | ((unsigned)h[3] << 16),
                 (unsigned)h[4] | ((unsigned)h[5] << 16), (unsigned)h[6] | ((unsigned)h[7] << 16) };
    M = (uint4){ (unsigned)m[0] | ((unsigned)m[1] << 16), (unsigned)m[2] | ((unsigned)m[3] << 16),
                 (unsigned)m[4] | ((unsigned)m[5] << 16), (unsigned)m[6] | ((unsigned)m[7] << 16) };
}

// ---------------- im2col: patches[tokid][k] (coalesced both sides) ----------------
__global__ __launch_bounds__(256)
void im2col_kernel(const float* __restrict__ x, float* __restrict__ patches)
{
    int idx = blockIdx.x*256 + threadIdx.x;   // tokid*256 + k
    int k = idx & 255, tokid = idx >> 8;
    int b = tokid / 576, n = tokid % 576;
    int hp = n / 24, wp = n % 24;
    patches[idx] = x[(size_t)b*147456 + (size_t)(hp*16 + (k >> 4))*384 + wp*16 + (k & 15)];
}

// ---------------- LayerNorm over D=768, one block per token ----------------
__global__ __launch_bounds__(256)
void ln_kernel(const float* __restrict__ in, float* __restrict__ out,
               const float* __restrict__ g, const float* __restrict__ bta)
{
    int tokid = blockIdx.x;
    const float* xr = in + (size_t)tokid*768;
    int t = threadIdx.x;
    float v0 = xr[t], v1 = xr[t+256], v2 = xr[t+512];
    float s = v0+v1+v2, q = v0*v0+v1*v1+v2*v2;
    for (int off = 32; off > 0; off >>= 1) {
        s += __shfl_down(s, off);
        q += __shfl_down(q, off);
    }
    __shared__ float ss[4], sq[4];
    int wv = t >> 6, ln = t & 63;
    if (ln == 0) { ss[wv] = s; sq[wv] = q; }
    __syncthreads();
    float ts = ss[0]+ss[1]+ss[2]+ss[3];
    float tq = sq[0]+sq[1]+sq[2]+sq[3];
    float mean = ts * (1.f/768.f);
    float var  = tq * (1.f/768.f) - mean*mean;
    float inv  = rsqrtf(var + 1e-5f);
    float* orow = out + (size_t)tokid*768;
    orow[t]     = (v0-mean)*inv*g[t]     + bta[t];
    orow[t+256] = (v1-mean)*inv*g[t+256] + bta[t+256];
    orow[t+512] = (v2-mean)*inv*g[t+512] + bta[t+512];
}

// ---------------- MFMA NT GEMM: C[row(m),n] = sum_k A[row(m),k]*Bw[n,k] (+bias) ----
// 2-limb fp16 split (h RN, m RN scaled x2048), 3 MFMA terms: hh -> acc1, hm+mh -> acc2;
// val = acc1 + acc2/2048. Dropped terms ~3*2^-22 relative: fp32-class (gate-flip safe).
// 128x128 tile, BK=32, 4 waves (2x2), each wave 64x64 = 4x4 frags of 16x16x32.
// LDS 4x[128][40] ushort (row stride 80B = 16B-aligned): frag reads 2-way (free).
// mode 0: C = val   1: C += val   2: C[gather] = gelu(val)   3: C[gather] += wgt*val
// mode 4: C = val + pos[(row%576)*768 + n]   (wgt arg doubles as pos pointer)
__global__ __launch_bounds__(256, 2)
void gemm_mfma(const float* __restrict__ A, const float* __restrict__ Bw,
               const float* __restrict__ bias, float* __restrict__ C,
               int M, int Nout, int K, int ldA, int ldC, int mode,
               const int* __restrict__ lists, const int* __restrict__ counts,
               const float* __restrict__ wgt)
{
    int Meff = M;
    const int* gather = nullptr;
    if (counts) {
        int e = blockIdx.z;
        Meff   = counts[e];
        gather = lists + e * TOK;
        Bw    += (size_t)e * Nout * K;
        bias  += (size_t)e * Nout;
    }
    int m0 = blockIdx.y << 7, n0 = blockIdx.x << 7;
    if (m0 >= Meff) return;

    __shared__ unsigned short Ah[128][40];
    __shared__ unsigned short Am[128][40];
    __shared__ unsigned short Bh[128][40];
    __shared__ unsigned short Bm[128][40];

    int t = threadIdx.x;
    // staging: thread t covers row (t>>1), k-half (t&1)*16 (16 floats)
    int srow = t >> 1;
    int koff = (t & 1) << 4;

    int ar = m0 + srow;
    long agrow = -1;
    if (ar < Meff) agrow = gather ? gather[ar] : ar;
    const float* Asrc = (agrow >= 0) ? (A + (size_t)agrow*ldA + koff) : nullptr;
    const float* Bsrc = Bw + (size_t)(n0 + srow)*K + koff;

    // compute mapping: wave (2x2), lane -> fragment coords
    int lane = t & 63;
    int wv   = t >> 6;
    int wm   = (wv >> 1) << 6;   // 0 / 64
    int wn   = (wv & 1) << 6;    // 0 / 64
    int r16  = lane & 15;
    int g    = lane >> 4;        // k-group 0..3 (8 k each)

    f32x4 acc1[4][4], acc2[4][4];
    #pragma unroll
    for (int i = 0; i < 4; ++i)
        #pragma unroll
        for (int j = 0; j < 4; ++j) {
            acc1[i][j] = (f32x4){0.f, 0.f, 0.f, 0.f};
            acc2[i][j] = (f32x4){0.f, 0.f, 0.f, 0.f};
        }

    float4 ra[4], rb[4];
    ra[0] = ra[1] = ra[2] = ra[3] = make_float4(0.f, 0.f, 0.f, 0.f);

    auto load_tile = [&](int k0) {
        if (Asrc) {
            ra[0] = *(const float4*)(Asrc + k0);
            ra[1] = *(const float4*)(Asrc + k0 + 4);
            ra[2] = *(const float4*)(Asrc + k0 + 8);
            ra[3] = *(const float4*)(Asrc + k0 + 12);
        }
        rb[0] = *(const float4*)(Bsrc + k0);
        rb[1] = *(const float4*)(Bsrc + k0 + 4);
        rb[2] = *(const float4*)(Bsrc + k0 + 8);
        rb[3] = *(const float4*)(Bsrc + k0 + 12);
    };

    auto stage = [&]() {
        uint4 H, M_;
        cvt2_pack8(ra[0], ra[1], H, M_);
        *(uint4*)&Ah[srow][koff]     = H;
        *(uint4*)&Am[srow][koff]     = M_;
        cvt2_pack8(ra[2], ra[3], H, M_);
        *(uint4*)&Ah[srow][koff + 8] = H;
        *(uint4*)&Am[srow][koff + 8] = M_;
        cvt2_pack8(rb[0], rb[1], H, M_);
        *(uint4*)&Bh[srow][koff]     = H;
        *(uint4*)&Bm[srow][koff]     = M_;
        cvt2_pack8(rb[2], rb[3], H, M_);
        *(uint4*)&Bh[srow][koff + 8] = H;
        *(uint4*)&Bm[srow][koff + 8] = M_;
    };

    load_tile(0);

    for (int k0 = 0; k0 < K; k0 += 32) {
        __syncthreads();          // previous compute done reading LDS
        stage();
        __syncthreads();
        if (k0 + 32 < K) load_tile(k0 + 32);   // prefetch hides under MFMA

        f16x8 fah[4], fam[4];
        #pragma unroll
        for (int i = 0; i < 4; ++i) {
            int ml = wm + i*16 + r16;
            fah[i] = *(const f16x8*)&Ah[ml][g*8];
            fam[i] = *(const f16x8*)&Am[ml][g*8];
        }
        #pragma unroll
        for (int j = 0; j < 4; ++j) {
            int nl = wn + j*16 + r16;
            f16x8 fbh = *(const f16x8*)&Bh[nl][g*8];
            f16x8 fbm = *(const f16x8*)&Bm[nl][g*8];
            #pragma unroll
            for (int i = 0; i < 4; ++i) {
                acc1[i][j] = __builtin_amdgcn_mfma_f32_16x16x32_f16(fah[i], fbh, acc1[i][j], 0, 0, 0);
                acc2[i][j] = __builtin_amdgcn_mfma_f32_16x16x32_f16(fah[i], fbm, acc2[i][j], 0, 0, 0);
                acc2[i][j] = __builtin_amdgcn_mfma_f32_16x16x32_f16(fam[i], fbh, acc2[i][j], 0, 0, 0);
            }
        }
    }

    // epilogue: lane holds D[(g*4+r)][r16] of each 16x16 frag
    const float MS = 1.0f / 2048.0f;
    float biasv[4];
    #pragma unroll
    for (int j = 0; j < 4; ++j) biasv[j] = bias[n0 + wn + j*16 + r16];

    #pragma unroll
    for (int i = 0; i < 4; ++i) {
        int mb = m0 + wm + i*16 + (g << 2);
        #pragma unroll
        for (int r = 0; r < 4; ++r) {
            int m = mb + r;
            if (m >= Meff) continue;
            int row = gather ? gather[m] : m;
            float* crow = C + (size_t)row*ldC + n0 + wn + r16;
            float w = (mode == 3) ? wgt[row] : 0.f;
            #pragma unroll
            for (int j = 0; j < 4; ++j) {
                float val = acc1[i][j][r] + acc2[i][j][r] * MS + biasv[j];
                float* cp = crow + j*16;
                if      (mode == 0) *cp = val;
                else if (mode == 1) *cp += val;
                else if (mode == 2) *cp = gelu_exact(val);
                else if (mode == 3) *cp += w * val;
                else {  // mode 4: patch embed, add positional embedding
                    *cp = val + wgt[(size_t)(row % 576)*768 + n0 + wn + j*16 + r16];
                }
            }
        }
    }
}

// ---------------- attention: one block = (16 q-rows, head, batch) ----------------
__global__ __launch_bounds__(256)
void attn_kernel(const float* __restrict__ qkv, float* __restrict__ attn)
{
    int q0 = blockIdx.x << 4;
    int h  = blockIdx.y;
    int b  = blockIdx.z;
    const float* base = qkv + (size_t)b * 576 * 2304;
    int qoff = h << 6, koff = 768 + (h<<6), voff = 1536 + (h<<6);
    __shared__ float qs[16][68], kt[16][68];
    __shared__ float sc[16][592];
    __shared__ float ssum[16];
    int t = threadIdx.x;
    int r = t >> 4, c4 = (t & 15) << 2;
    *(float4*)&qs[r][c4] = *(const float4*)&base[(size_t)(q0 + r)*2304 + qoff + c4];
    __syncthreads();
    int jj = t & 15;
    for (int j0 = 0; j0 < 576; j0 += 16) {
        *(float4*)&kt[r][c4] = *(const float4*)&base[(size_t)(j0 + r)*2304 + koff + c4];
        __syncthreads();
        float s = 0.f;
        #pragma unroll
        for (int d = 0; d < 64; d += 4) {
            float qa[4], ka[4];
            *(float4*)qa = *(const float4*)&qs[r][d];
            *(float4*)ka = *(const float4*)&kt[jj][d];
            s = fmaf(qa[0],ka[0], fmaf(qa[1],ka[1], fmaf(qa[2],ka[2], fmaf(qa[3],ka[3], s))));
        }
        sc[r][j0 + jj] = s * 0.125f;
        __syncthreads();
    }
    // softmax per row: 16 threads per row (same wave), keep un-normalized exp + sum
    {
        int row = t >> 4, l16 = t & 15;
        float mx = -3.4e38f;
        for (int j = l16; j < 576; j += 16) mx = fmaxf(mx, sc[row][j]);
        #pragma unroll
        for (int off = 8; off > 0; off >>= 1) mx = fmaxf(mx, __shfl_xor(mx, off, 16));
        float sum = 0.f;
        for (int j = l16; j < 576; j += 16) {
            float e = expf(sc[row][j] - mx);
            sc[row][j] = e;
            sum += e;
        }
        #pragma unroll
        for (int off = 8; off > 0; off >>= 1) sum += __shfl_xor(sum, off, 16);
        if (l16 == 0) ssum[row] = sum;
    }
    __syncthreads();
    // PV: thread handles (d = t&63, rows rb..rb+3); V staged through LDS (kt reused)
    int d = t & 63, rb = (t >> 6) << 2;
    float acc[4] = {0.f,0.f,0.f,0.f};
    for (int j0 = 0; j0 < 576; j0 += 16) {
        *(float4*)&kt[r][c4] = *(const float4*)&base[(size_t)(j0 + r)*2304 + voff + c4];
        __syncthreads();
        #pragma unroll
        for (int jj4 = 0; jj4 < 16; jj4 += 4) {
            float a0[4], a1[4], a2[4], a3[4];
            *(float4*)a0 = *(const float4*)&sc[rb+0][j0+jj4];
            *(float4*)a1 = *(const float4*)&sc[rb+1][j0+jj4];
            *(float4*)a2 = *(const float4*)&sc[rb+2][j0+jj4];
            *(float4*)a3 = *(const float4*)&sc[rb+3][j0+jj4];
            #pragma unroll
            for (int u = 0; u < 4; ++u) {
                float v = kt[jj4+u][d];
                acc[0] = fmaf(a0[u], v, acc[0]);
                acc[1] = fmaf(a1[u], v, acc[1]);
                acc[2] = fmaf(a2[u], v, acc[2]);
                acc[3] = fmaf(a3[u], v, acc[3]);
            }
        }
        __syncthreads();
    }
    #pragma unroll
    for (int i = 0; i < 4; ++i)
        attn[(size_t)(b*576 + q0 + rb + i)*768 + qoff + d] = acc[i] / ssum[rb+i];
}

// ---------------- gate: scores -> argmax -> expert lists ----------------
__global__ __launch_bounds__(256)
void gate_kernel(const float* __restrict__ h2, const float* __restrict__ gw,
                 const float* __restrict__ gb, float* __restrict__ wgt,
                 int* __restrict__ lists, int* __restrict__ counts)
{
    int tokid = blockIdx.x;
    int t = threadIdx.x;
    const float* hr = h2 + (size_t)tokid*768;
    float p0=0.f,p1=0.f,p2=0.f,p3=0.f;
    for (int k = t; k < 768; k += 256) {
        float hv = hr[k];
        p0 = fmaf(hv, gw[k],        p0);
        p1 = fmaf(hv, gw[768 + k],  p1);
        p2 = fmaf(hv, gw[1536 + k], p2);
        p3 = fmaf(hv, gw[2304 + k], p3);
    }
    for (int off = 32; off > 0; off >>= 1) {
        p0 += __shfl_down(p0, off);
        p1 += __shfl_down(p1, off);
        p2 += __shfl_down(p2, off);
        p3 += __shfl_down(p3, off);
    }
    __shared__ float red[4][4];
    int wv = t >> 6, ln = t & 63;
    if (ln == 0) { red[wv][0]=p0; red[wv][1]=p1; red[wv][2]=p2; red[wv][3]=p3; }
    __syncthreads();
    if (t == 0) {
        float s[4];
        #pragma unroll
        for (int e = 0; e < 4; ++e)
            s[e] = red[0][e]+red[1][e]+red[2][e]+red[3][e] + gb[e];
        int best = 0; float bv = s[0];
        #pragma unroll
        for (int e = 1; e < 4; ++e) if (s[e] > bv) { bv = s[e]; best = e; }  // first-max tie-break
        wgt[tokid] = bv;
        int pos = atomicAdd(&counts[best], 1);
        lists[best*TOK + pos] = tokid;
    }
}

__global__ void zero_counts(int* counts) { if (threadIdx.x < 4) counts[threadIdx.x] = 0; }

// ---------------- final b (h w) c -> b c h w ----------------
__global__ __launch_bounds__(256)
void out_transpose(const float* __restrict__ tok, float* __restrict__ out)
{
    int idx = blockIdx.x*256 + threadIdx.x;   // ((b*768+d)*24+hp)*24+wp
    int wp = idx % 24;
    int hp = (idx / 24) % 24;
    int d  = (idx / 576) % 768;
    int b  = idx / (576*768);
    out[idx] = tok[(size_t)(b*576 + hp*24 + wp)*768 + d];
}

extern "C" void kernel_launch(void* const* d_in, const int* in_sizes, int n_in,
                              void* d_out, int out_size, void* d_ws, size_t ws_size,
                              hipStream_t stream)
{
    const float* x       = (const float*)d_in[0];
    const float* patch_w = (const float*)d_in[1];
    const float* patch_b = (const float*)d_in[2];
    const float* pos     = (const float*)d_in[3];
    const float* ln1_g   = (const float*)d_in[4];
    const float* ln1_b   = (const float*)d_in[5];
    const float* qkv_w   = (const float*)d_in[6];
    const float* qkv_b   = (const float*)d_in[7];
    const float* out_w   = (const float*)d_in[8];
    const float* out_b   = (const float*)d_in[9];
    const float* ln2_g   = (const float*)d_in[10];
    const float* ln2_b   = (const float*)d_in[11];
    const float* gate_w  = (const float*)d_in[12];
    const float* gate_b  = (const float*)d_in[13];
    const float* w1      = (const float*)d_in[14];
    const float* b1      = (const float*)d_in[15];
    const float* w2      = (const float*)d_in[16];
    const float* b2      = (const float*)d_in[17];
    float* out = (float*)d_out;

    // workspace layout (floats): tok | h | scratch{qkv,attn} (hid & patches alias scratch)
    //                            | wgt | lists | counts
    float* ws    = (float*)d_ws;
    float* tok   = ws;                       // 3,538,944
    float* h     = ws + 3538944;             // 3,538,944
    float* scr   = ws + 7077888;             // 14,155,776 (qkv 10,616,832 + attn 3,538,944)
    float* qkv   = scr;
    float* attn  = scr + 10616832;
    float* hid   = scr;                      // aliases qkv+attn (dead by FFN time)
    float* patches = scr;                    // 4608*256 = 1,179,648 (dead before layer loop)
    float* wgt   = ws + 21233664;            // 4608
    int*   lists = (int*)(ws + 21238272);    // 4*4608
    int*   counts= (int*)(ws + 21256704);    // 4

    // patch embed = im2col + MFMA GEMM (mode 4 adds pos embed)
    im2col_kernel<<<4608, 256, 0, stream>>>(x, patches);
    gemm_mfma<<<dim3(6,36,1), 256, 0, stream>>>(patches, patch_w, patch_b, tok,
                                                4608, 768, 256, 256, 768, 4,
                                                nullptr, nullptr, pos);

    for (int l = 0; l < 12; ++l) {
        ln_kernel<<<4608, 256, 0, stream>>>(tok, h, ln1_g + l*768, ln1_b + l*768);
        gemm_mfma<<<dim3(18,36,1), 256, 0, stream>>>(h, qkv_w + (size_t)l*2304*768, qkv_b + l*2304,
                                                     qkv, 4608, 2304, 768, 768, 2304, 0,
                                                     nullptr, nullptr, nullptr);
        attn_kernel<<<dim3(36,12,8), 256, 0, stream>>>(qkv, attn);
        gemm_mfma<<<dim3(6,36,1), 256, 0, stream>>>(attn, out_w + (size_t)l*768*768, out_b + l*768,
                                                    tok, 4608, 768, 768, 768, 768, 1,
                                                    nullptr, nullptr, nullptr);
        ln_kernel<<<4608, 256, 0, stream>>>(tok, h, ln2_g + l*768, ln2_b + l*768);
        zero_counts<<<1, 64, 0, stream>>>(counts);
        gate_kernel<<<4608, 256, 0, stream>>>(h, gate_w + l*3072, gate_b + l*4, wgt, lists, counts);
        gemm_mfma<<<dim3(24,36,4), 256, 0, stream>>>(h, w1 + (size_t)l*4*3072*768, b1 + (size_t)l*4*3072,
                                                     hid, 4608, 3072, 768, 768, 3072, 2,
                                                     lists, counts, nullptr);
        gemm_mfma<<<dim3(6,36,4), 256, 0, stream>>>(hid, w2 + (size_t)l*4*768*3072, b2 + (size_t)l*4*768,
                                                    tok, 4608, 768, 3072, 3072, 768, 3,
                                                    lists, counts, wgt);
    }
    out_transpose<<<13824, 256, 0, stream>>>(tok, out);
}

// Round 6
// 8236.868 us; speedup vs baseline: 2.4018x; 1.3946x over previous
//
#include <hip/hip_runtime.h>
#include <cmath>

#define TOK 4608      // B*N
#define DMODEL 768

typedef __attribute__((ext_vector_type(8))) _Float16 f16x8;
typedef __attribute__((ext_vector_type(4))) float f32x4;

__device__ __forceinline__ float gelu_exact(float x) {
    return 0.5f * x * (1.0f + erff(x * 0.70710678118654752440f));
}

// 2-limb fp16 decomposition, RN both limbs. x = h + m/2048 + delta, |delta| <= 2^-22 |x|.
// m is pre-scaled by 2048 so it is never subnormal (robust to MFMA input-denorm flush);
// the hm/mh accumulator is scaled back by 1/2048 in the epilogue.
__device__ __forceinline__ void cvt2(float x, unsigned short& h, unsigned short& m)
{
    _Float16 hf = (_Float16)x;                  // v_cvt_f16_f32 (RN)
    float r = (x - (float)hf) * 2048.0f;        // exact residual (Sterbenz), rescaled
    _Float16 mf = (_Float16)r;
    h = __builtin_bit_cast(unsigned short, hf);
    m = __builtin_bit_cast(unsigned short, mf);
}

__device__ __forceinline__ void cvt2_pack8(const float4 a, const float4 b,
                                           uint4& H, uint4& M)
{
    unsigned short h[8], m[8];
    cvt2(a.x, h[0], m[0]); cvt2(a.y, h[1], m[1]);
    cvt2(a.z, h[2], m[2]); cvt2(a.w, h[3], m[3]);
    cvt2(b.x, h[4], m[4]); cvt2(b.y, h[5], m[5]);
    cvt2(b.z, h[6], m[6]); cvt2(b.w, h[7], m[7]);
    H = (uint4){ (unsigned)h[0] | ((unsigned)h[1] << 16), (unsigned)h[2] | ((unsigned)h[3] << 16),
                 (unsigned)h[4] | ((unsigned)h[5] << 16), (unsigned)h[6] | ((unsigned)h[7] << 16) };
    M = (uint4){ (unsigned)m[0] | ((unsigned)m[1] << 16), (unsigned)m[2] | ((unsigned)m[3] << 16),
                 (unsigned)m[4] | ((unsigned)m[5] << 16), (unsigned)m[6] | ((unsigned)m[7] << 16) };
}

// ---------------- im2col: patches[tokid][k] (coalesced both sides) ----------------
__global__ __launch_bounds__(256)
void im2col_kernel(const float* __restrict__ x, float* __restrict__ patches)
{
    int idx = blockIdx.x*256 + threadIdx.x;   // tokid*256 + k
    int k = idx & 255, tokid = idx >> 8;
    int b = tokid / 576, n = tokid % 576;
    int hp = n / 24, wp = n % 24;
    patches[idx] = x[(size_t)b*147456 + (size_t)(hp*16 + (k >> 4))*384 + wp*16 + (k & 15)];
}

// ---------------- LayerNorm over D=768, one block per token ----------------
__global__ __launch_bounds__(256)
void ln_kernel(const float* __restrict__ in, float* __restrict__ out,
               const float* __restrict__ g, const float* __restrict__ bta)
{
    int tokid = blockIdx.x;
    const float* xr = in + (size_t)tokid*768;
    int t = threadIdx.x;
    float v0 = xr[t], v1 = xr[t+256], v2 = xr[t+512];
    float s = v0+v1+v2, q = v0*v0+v1*v1+v2*v2;
    for (int off = 32; off > 0; off >>= 1) {
        s += __shfl_down(s, off);
        q += __shfl_down(q, off);
    }
    __shared__ float ss[4], sq[4];
    int wv = t >> 6, ln = t & 63;
    if (ln == 0) { ss[wv] = s; sq[wv] = q; }
    __syncthreads();
    float ts = ss[0]+ss[1]+ss[2]+ss[3];
    float tq = sq[0]+sq[1]+sq[2]+sq[3];
    float mean = ts * (1.f/768.f);
    float var  = tq * (1.f/768.f) - mean*mean;
    float inv  = rsqrtf(var + 1e-5f);
    float* orow = out + (size_t)tokid*768;
    orow[t]     = (v0-mean)*inv*g[t]     + bta[t];
    orow[t+256] = (v1-mean)*inv*g[t+256] + bta[t+256];
    orow[t+512] = (v2-mean)*inv*g[t+512] + bta[t+512];
}

// ---------------- MFMA NT GEMM: C[row(m),n] = sum_k A[row(m),k]*Bw[n,k] (+bias) ----
// 2-limb fp16 split (h RN, m RN scaled x2048), 3 MFMA terms: hh -> acc1, hm+mh -> acc2;
// val = acc1 + acc2/2048. Dropped terms ~3*2^-22 relative: fp32-class (gate-flip safe).
// 128x128 tile, BK=32, 4 waves (2x2), each wave 64x64 = 4x4 frags of 16x16x32.
// LDS 4x[128][40] ushort (row stride 80B = 16B-aligned): frag reads 2-way (free).
// mode 0: C = val   1: C += val   2: C[gather] = gelu(val)   3: C[gather] += wgt*val
// mode 4: C = val + pos[(row%576)*768 + n]   (wgt arg doubles as pos pointer)
__global__ __launch_bounds__(256, 2)
void gemm_mfma(const float* __restrict__ A, const float* __restrict__ Bw,
               const float* __restrict__ bias, float* __restrict__ C,
               int M, int Nout, int K, int ldA, int ldC, int mode,
               const int* __restrict__ lists, const int* __restrict__ counts,
               const float* __restrict__ wgt)
{
    int Meff = M;
    const int* gather = nullptr;
    if (counts) {
        int e = blockIdx.z;
        Meff   = counts[e];
        gather = lists + e * TOK;
        Bw    += (size_t)e * Nout * K;
        bias  += (size_t)e * Nout;
    }
    int m0 = blockIdx.y << 7, n0 = blockIdx.x << 7;
    if (m0 >= Meff) return;

    __shared__ unsigned short Ah[128][40];
    __shared__ unsigned short Am[128][40];
    __shared__ unsigned short Bh[128][40];
    __shared__ unsigned short Bm[128][40];

    int t = threadIdx.x;
    // staging: thread t covers row (t>>1), k-half (t&1)*16 (16 floats)
    int srow = t >> 1;
    int koff = (t & 1) << 4;

    int ar = m0 + srow;
    long agrow = -1;
    if (ar < Meff) agrow = gather ? gather[ar] : ar;
    const float* Asrc = (agrow >= 0) ? (A + (size_t)agrow*ldA + koff) : nullptr;
    const float* Bsrc = Bw + (size_t)(n0 + srow)*K + koff;

    // compute mapping: wave (2x2), lane -> fragment coords
    int lane = t & 63;
    int wv   = t >> 6;
    int wm   = (wv >> 1) << 6;   // 0 / 64
    int wn   = (wv & 1) << 6;    // 0 / 64
    int r16  = lane & 15;
    int g    = lane >> 4;        // k-group 0..3 (8 k each)

    f32x4 acc1[4][4], acc2[4][4];
    #pragma unroll
    for (int i = 0; i < 4; ++i)
        #pragma unroll
        for (int j = 0; j < 4; ++j) {
            acc1[i][j] = (f32x4){0.f, 0.f, 0.f, 0.f};
            acc2[i][j] = (f32x4){0.f, 0.f, 0.f, 0.f};
        }

    float4 ra[4], rb[4];
    ra[0] = ra[1] = ra[2] = ra[3] = make_float4(0.f, 0.f, 0.f, 0.f);

    auto load_tile = [&](int k0) {
        if (Asrc) {
            ra[0] = *(const float4*)(Asrc + k0);
            ra[1] = *(const float4*)(Asrc + k0 + 4);
            ra[2] = *(const float4*)(Asrc + k0 + 8);
            ra[3] = *(const float4*)(Asrc + k0 + 12);
        }
        rb[0] = *(const float4*)(Bsrc + k0);
        rb[1] = *(const float4*)(Bsrc + k0 + 4);
        rb[2] = *(const float4*)(Bsrc + k0 + 8);
        rb[3] = *(const float4*)(Bsrc + k0 + 12);
    };

    auto stage = [&]() {
        uint4 H, M_;
        cvt2_pack8(ra[0], ra[1], H, M_);
        *(uint4*)&Ah[srow][koff]     = H;
        *(uint4*)&Am[srow][koff]     = M_;
        cvt2_pack8(ra[2], ra[3], H, M_);
        *(uint4*)&Ah[srow][koff + 8] = H;
        *(uint4*)&Am[srow][koff + 8] = M_;
        cvt2_pack8(rb[0], rb[1], H, M_);
        *(uint4*)&Bh[srow][koff]     = H;
        *(uint4*)&Bm[srow][koff]     = M_;
        cvt2_pack8(rb[2], rb[3], H, M_);
        *(uint4*)&Bh[srow][koff + 8] = H;
        *(uint4*)&Bm[srow][koff + 8] = M_;
    };

    load_tile(0);

    for (int k0 = 0; k0 < K; k0 += 32) {
        __syncthreads();          // previous compute done reading LDS
        stage();
        __syncthreads();
        if (k0 + 32 < K) load_tile(k0 + 32);   // prefetch hides under MFMA

        f16x8 fah[4], fam[4];
        #pragma unroll
        for (int i = 0; i < 4; ++i) {
            int ml = wm + i*16 + r16;
            fah[i] = *(const f16x8*)&Ah[ml][g*8];
            fam[i] = *(const f16x8*)&Am[ml][g*8];
        }
        #pragma unroll
        for (int j = 0; j < 4; ++j) {
            int nl = wn + j*16 + r16;
            f16x8 fbh = *(const f16x8*)&Bh[nl][g*8];
            f16x8 fbm = *(const f16x8*)&Bm[nl][g*8];
            #pragma unroll
            for (int i = 0; i < 4; ++i) {
                acc1[i][j] = __builtin_amdgcn_mfma_f32_16x16x32_f16(fah[i], fbh, acc1[i][j], 0, 0, 0);
                acc2[i][j] = __builtin_amdgcn_mfma_f32_16x16x32_f16(fah[i], fbm, acc2[i][j], 0, 0, 0);
                acc2[i][j] = __builtin_amdgcn_mfma_f32_16x16x32_f16(fam[i], fbh, acc2[i][j], 0, 0, 0);
            }
        }
    }

    // epilogue: lane holds D[(g*4+r)][r16] of each 16x16 frag
    const float MS = 1.0f / 2048.0f;
    float biasv[4];
    #pragma unroll
    for (int j = 0; j < 4; ++j) biasv[j] = bias[n0 + wn + j*16 + r16];

    #pragma unroll
    for (int i = 0; i < 4; ++i) {
        int mb = m0 + wm + i*16 + (g << 2);
        #pragma unroll
        for (int r = 0; r < 4; ++r) {
            int m = mb + r;
            if (m >= Meff) continue;
            int row = gather ? gather[m] : m;
            float* crow = C + (size_t)row*ldC + n0 + wn + r16;
            float w = (mode == 3) ? wgt[row] : 0.f;
            #pragma unroll
            for (int j = 0; j < 4; ++j) {
                float val = acc1[i][j][r] + acc2[i][j][r] * MS + biasv[j];
                float* cp = crow + j*16;
                if      (mode == 0) *cp = val;
                else if (mode == 1) *cp += val;
                else if (mode == 2) *cp = gelu_exact(val);
                else if (mode == 3) *cp += w * val;
                else {  // mode 4: patch embed, add positional embedding
                    *cp = val + wgt[(size_t)(row % 576)*768 + n0 + wn + j*16 + r16];
                }
            }
        }
    }
}

// ---------------- attention (MFMA, flash-style): one block = 64 q-rows x (head, batch)
// 2-limb fp16 for Q,K,V and P; dual accumulators (hh / cross-terms x2048).
// 4 waves, each owns 16 q-rows. Per 64-col tile: QK^T -> online softmax (regs) ->
// P limbs via LDS transpose -> PV. LDS rows [64][72] ushort: 144B stride, 16B-aligned,
// frag reads conflict-free (stride = 4 mod 32 dwords, 8-lane phases).
__global__ __launch_bounds__(256)
void attn_kernel(const float* __restrict__ qkv, float* __restrict__ attn)
{
    int q0 = blockIdx.x << 6;
    int h  = blockIdx.y;
    int b  = blockIdx.z;
    const float* base = qkv + (size_t)b * 576 * 2304;
    int qoff = h << 6, koff = 768 + (h << 6), voff = 1536 + (h << 6);

    __shared__ unsigned short Qh[64][72], Qm[64][72];
    __shared__ unsigned short Kh[64][72], Km[64][72];
    __shared__ unsigned short Vth[64][72], Vtm[64][72];   // transposed: [d][j]
    __shared__ unsigned short Ph[64][72], Pm[64][72];

    int t    = threadIdx.x;
    int lane = t & 63;
    int wq   = t >> 6;           // wave id -> q-subtile
    int l15  = lane & 15;
    int g    = lane >> 4;

    int srow = t >> 2;           // staging row 0..63
    int sq   = t & 3;            // quarter

    // ---- stage Q (rows q0+srow, d = sq*16 .. +15) ----
    {
        const float* src = &base[(size_t)(q0 + srow)*2304 + qoff + (sq << 4)];
        #pragma unroll
        for (int k = 0; k < 16; k += 4) {
            float4 v = *(const float4*)(src + k);
            ushort4 hh, mm;
            cvt2(v.x, hh.x, mm.x); cvt2(v.y, hh.y, mm.y);
            cvt2(v.z, hh.z, mm.z); cvt2(v.w, hh.w, mm.w);
            *(ushort4*)&Qh[srow][(sq << 4) + k] = hh;
            *(ushort4*)&Qm[srow][(sq << 4) + k] = mm;
        }
    }
    __syncthreads();

    // Q fragments (row = wq*16+l15), cached for the whole block
    f16x8 fqh[2], fqm[2];
    #pragma unroll
    for (int ks = 0; ks < 2; ++ks) {
        fqh[ks] = *(const f16x8*)&Qh[wq*16 + l15][ks*32 + g*8];
        fqm[ks] = *(const f16x8*)&Qm[wq*16 + l15][ks*32 + g*8];
    }

    // prefetch K/V tile 0
    float4 rk[4], rv[4];
    {
        const float* ks_ = &base[(size_t)srow*2304 + koff + (sq << 4)];
        const float* vs_ = &base[(size_t)srow*2304 + voff + (sq << 2)];
        #pragma unroll
        for (int k = 0; k < 4; ++k) rk[k] = *(const float4*)(ks_ + 4*k);
        #pragma unroll
        for (int k = 0; k < 4; ++k) rv[k] = *(const float4*)(vs_ + 16*k);
    }

    f32x4 o1[4], o2[4];
    #pragma unroll
    for (int df = 0; df < 4; ++df) {
        o1[df] = (f32x4){0.f,0.f,0.f,0.f};
        o2[df] = (f32x4){0.f,0.f,0.f,0.f};
    }
    float m_[4] = {-3.4e38f,-3.4e38f,-3.4e38f,-3.4e38f};
    float l_[4] = {0.f,0.f,0.f,0.f};
    const float MS = 1.0f / 2048.0f;

    for (int j0 = 0; j0 < 576; j0 += 64) {
        __syncthreads();   // previous tile's LDS reads done
        // stage K (natural [j][d], b64 writes)
        #pragma unroll
        for (int k = 0; k < 4; ++k) {
            ushort4 hh, mm;
            cvt2(rk[k].x, hh.x, mm.x); cvt2(rk[k].y, hh.y, mm.y);
            cvt2(rk[k].z, hh.z, mm.z); cvt2(rk[k].w, hh.w, mm.w);
            *(ushort4*)&Kh[srow][(sq << 4) + 4*k] = hh;
            *(ushort4*)&Km[srow][(sq << 4) + 4*k] = mm;
        }
        // stage V transposed ([d][j], b16 writes; d = sq*4 + 16k + e)
        #pragma unroll
        for (int k = 0; k < 4; ++k) {
            ushort4 hh, mm;
            cvt2(rv[k].x, hh.x, mm.x); cvt2(rv[k].y, hh.y, mm.y);
            cvt2(rv[k].z, hh.z, mm.z); cvt2(rv[k].w, hh.w, mm.w);
            int dbase = (sq << 2) + (k << 4);
            Vth[dbase+0][srow] = hh.x; Vtm[dbase+0][srow] = mm.x;
            Vth[dbase+1][srow] = hh.y; Vtm[dbase+1][srow] = mm.y;
            Vth[dbase+2][srow] = hh.z; Vtm[dbase+2][srow] = mm.z;
            Vth[dbase+3][srow] = hh.w; Vtm[dbase+3][srow] = mm.w;
        }
        __syncthreads();
        // prefetch next tile (hides under compute)
        int jn = j0 + 64;
        if (jn < 576) {
            const float* ks_ = &base[(size_t)(jn + srow)*2304 + koff + (sq << 4)];
            const float* vs_ = &base[(size_t)(jn + srow)*2304 + voff + (sq << 2)];
            #pragma unroll
            for (int k = 0; k < 4; ++k) rk[k] = *(const float4*)(ks_ + 4*k);
            #pragma unroll
            for (int k = 0; k < 4; ++k) rv[k] = *(const float4*)(vs_ + 16*k);
        }

        // ---- QK^T ----
        f32x4 s1[4], s2[4];
        #pragma unroll
        for (int jf = 0; jf < 4; ++jf) {
            s1[jf] = (f32x4){0.f,0.f,0.f,0.f};
            s2[jf] = (f32x4){0.f,0.f,0.f,0.f};
        }
        #pragma unroll
        for (int jf = 0; jf < 4; ++jf) {
            #pragma unroll
            for (int ks = 0; ks < 2; ++ks) {
                f16x8 fkh = *(const f16x8*)&Kh[jf*16 + l15][ks*32 + g*8];
                f16x8 fkm = *(const f16x8*)&Km[jf*16 + l15][ks*32 + g*8];
                s1[jf] = __builtin_amdgcn_mfma_f32_16x16x32_f16(fqh[ks], fkh, s1[jf], 0, 0, 0);
                s2[jf] = __builtin_amdgcn_mfma_f32_16x16x32_f16(fqh[ks], fkm, s2[jf], 0, 0, 0);
                s2[jf] = __builtin_amdgcn_mfma_f32_16x16x32_f16(fqm[ks], fkh, s2[jf], 0, 0, 0);
            }
        }
        float p[4][4];
        #pragma unroll
        for (int jf = 0; jf < 4; ++jf)
            #pragma unroll
            for (int r = 0; r < 4; ++r)
                p[jf][r] = (s1[jf][r] + s2[jf][r]*MS) * 0.125f;

        // ---- online softmax (rows g*4+r; reduce over 16 lanes sharing g) ----
        #pragma unroll
        for (int r = 0; r < 4; ++r) {
            float tm = fmaxf(fmaxf(p[0][r], p[1][r]), fmaxf(p[2][r], p[3][r]));
            #pragma unroll
            for (int off = 8; off > 0; off >>= 1) tm = fmaxf(tm, __shfl_xor(tm, off, 16));
            float mn = fmaxf(m_[r], tm);
            float f  = expf(m_[r] - mn);
            m_[r] = mn;
            l_[r] *= f;
            #pragma unroll
            for (int df = 0; df < 4; ++df) { o1[df][r] *= f; o2[df][r] *= f; }
            float ps = 0.f;
            #pragma unroll
            for (int jf = 0; jf < 4; ++jf) {
                p[jf][r] = expf(p[jf][r] - mn);
                ps += p[jf][r];
            }
            #pragma unroll
            for (int off = 8; off > 0; off >>= 1) ps += __shfl_xor(ps, off, 16);
            l_[r] += ps;
        }
        // write P limbs (own wave's rows only -> no barrier, lgkmcnt suffices)
        #pragma unroll
        for (int jf = 0; jf < 4; ++jf)
            #pragma unroll
            for (int r = 0; r < 4; ++r) {
                unsigned short ph, pm;
                cvt2(p[jf][r], ph, pm);
                Ph[wq*16 + g*4 + r][jf*16 + l15] = ph;
                Pm[wq*16 + g*4 + r][jf*16 + l15] = pm;
            }

        // ---- PV ----
        #pragma unroll
        for (int ks = 0; ks < 2; ++ks) {
            f16x8 fph = *(const f16x8*)&Ph[wq*16 + l15][ks*32 + g*8];
            f16x8 fpm = *(const f16x8*)&Pm[wq*16 + l15][ks*32 + g*8];
            #pragma unroll
            for (int df = 0; df < 4; ++df) {
                f16x8 fvh = *(const f16x8*)&Vth[df*16 + l15][ks*32 + g*8];
                f16x8 fvm = *(const f16x8*)&Vtm[df*16 + l15][ks*32 + g*8];
                o1[df] = __builtin_amdgcn_mfma_f32_16x16x32_f16(fph, fvh, o1[df], 0, 0, 0);
                o2[df] = __builtin_amdgcn_mfma_f32_16x16x32_f16(fph, fvm, o2[df], 0, 0, 0);
                o2[df] = __builtin_amdgcn_mfma_f32_16x16x32_f16(fpm, fvh, o2[df], 0, 0, 0);
            }
        }
    }

    // ---- epilogue: out = (o1 + o2/2048) / l ----
    #pragma unroll
    for (int r = 0; r < 4; ++r) {
        float inv = 1.f / l_[r];
        size_t row = (size_t)(b*576 + q0 + wq*16 + g*4 + r)*768 + qoff + l15;
        #pragma unroll
        for (int df = 0; df < 4; ++df)
            attn[row + df*16] = (o1[df][r] + o2[df][r]*MS) * inv;
    }
}

// ---------------- gate: scores -> argmax -> expert lists ----------------
__global__ __launch_bounds__(256)
void gate_kernel(const float* __restrict__ h2, const float* __restrict__ gw,
                 const float* __restrict__ gb, float* __restrict__ wgt,
                 int* __restrict__ lists, int* __restrict__ counts)
{
    int tokid = blockIdx.x;
    int t = threadIdx.x;
    const float* hr = h2 + (size_t)tokid*768;
    float p0=0.f,p1=0.f,p2=0.f,p3=0.f;
    for (int k = t; k < 768; k += 256) {
        float hv = hr[k];
        p0 = fmaf(hv, gw[k],        p0);
        p1 = fmaf(hv, gw[768 + k],  p1);
        p2 = fmaf(hv, gw[1536 + k], p2);
        p3 = fmaf(hv, gw[2304 + k], p3);
    }
    for (int off = 32; off > 0; off >>= 1) {
        p0 += __shfl_down(p0, off);
        p1 += __shfl_down(p1, off);
        p2 += __shfl_down(p2, off);
        p3 += __shfl_down(p3, off);
    }
    __shared__ float red[4][4];
    int wv = t >> 6, ln = t & 63;
    if (ln == 0) { red[wv][0]=p0; red[wv][1]=p1; red[wv][2]=p2; red[wv][3]=p3; }
    __syncthreads();
    if (t == 0) {
        float s[4];
        #pragma unroll
        for (int e = 0; e < 4; ++e)
            s[e] = red[0][e]+red[1][e]+red[2][e]+red[3][e] + gb[e];
        int best = 0; float bv = s[0];
        #pragma unroll
        for (int e = 1; e < 4; ++e) if (s[e] > bv) { bv = s[e]; best = e; }  // first-max tie-break
        wgt[tokid] = bv;
        int pos = atomicAdd(&counts[best], 1);
        lists[best*TOK + pos] = tokid;
    }
}

__global__ void zero_counts(int* counts) { if (threadIdx.x < 4) counts[threadIdx.x] = 0; }

// ---------------- final b (h w) c -> b c h w ----------------
__global__ __launch_bounds__(256)
void out_transpose(const float* __restrict__ tok, float* __restrict__ out)
{
    int idx = blockIdx.x*256 + threadIdx.x;   // ((b*768+d)*24+hp)*24+wp
    int wp = idx % 24;
    int hp = (idx / 24) % 24;
    int d  = (idx / 576) % 768;
    int b  = idx / (576*768);
    out[idx] = tok[(size_t)(b*576 + hp*24 + wp)*768 + d];
}

extern "C" void kernel_launch(void* const* d_in, const int* in_sizes, int n_in,
                              void* d_out, int out_size, void* d_ws, size_t ws_size,
                              hipStream_t stream)
{
    const float* x       = (const float*)d_in[0];
    const float* patch_w = (const float*)d_in[1];
    const float* patch_b = (const float*)d_in[2];
    const float* pos     = (const float*)d_in[3];
    const float* ln1_g   = (const float*)d_in[4];
    const float* ln1_b   = (const float*)d_in[5];
    const float* qkv_w   = (const float*)d_in[6];
    const float* qkv_b   = (const float*)d_in[7];
    const float* out_w   = (const float*)d_in[8];
    const float* out_b   = (const float*)d_in[9];
    const float* ln2_g   = (const float*)d_in[10];
    const float* ln2_b   = (const float*)d_in[11];
    const float* gate_w  = (const float*)d_in[12];
    const float* gate_b  = (const float*)d_in[13];
    const float* w1      = (const float*)d_in[14];
    const float* b1      = (const float*)d_in[15];
    const float* w2      = (const float*)d_in[16];
    const float* b2      = (const float*)d_in[17];
    float* out = (float*)d_out;

    // workspace layout (floats): tok | h | scratch{qkv,attn} (hid & patches alias scratch)
    //                            | wgt | lists | counts
    float* ws    = (float*)d_ws;
    float* tok   = ws;                       // 3,538,944
    float* h     = ws + 3538944;             // 3,538,944
    float* scr   = ws + 7077888;             // 14,155,776 (qkv 10,616,832 + attn 3,538,944)
    float* qkv   = scr;
    float* attn  = scr + 10616832;
    float* hid   = scr;                      // aliases qkv+attn (dead by FFN time)
    float* patches = scr;                    // 4608*256 = 1,179,648 (dead before layer loop)
    float* wgt   = ws + 21233664;            // 4608
    int*   lists = (int*)(ws + 21238272);    // 4*4608
    int*   counts= (int*)(ws + 21256704);    // 4

    // patch embed = im2col + MFMA GEMM (mode 4 adds pos embed)
    im2col_kernel<<<4608, 256, 0, stream>>>(x, patches);
    gemm_mfma<<<dim3(6,36,1), 256, 0, stream>>>(patches, patch_w, patch_b, tok,
                                                4608, 768, 256, 256, 768, 4,
                                                nullptr, nullptr, pos);

    for (int l = 0; l < 12; ++l) {
        ln_kernel<<<4608, 256, 0, stream>>>(tok, h, ln1_g + l*768, ln1_b + l*768);
        gemm_mfma<<<dim3(18,36,1), 256, 0, stream>>>(h, qkv_w + (size_t)l*2304*768, qkv_b + l*2304,
                                                     qkv, 4608, 2304, 768, 768, 2304, 0,
                                                     nullptr, nullptr, nullptr);
        attn_kernel<<<dim3(9,12,8), 256, 0, stream>>>(qkv, attn);
        gemm_mfma<<<dim3(6,36,1), 256, 0, stream>>>(attn, out_w + (size_t)l*768*768, out_b + l*768,
                                                    tok, 4608, 768, 768, 768, 768, 1,
                                                    nullptr, nullptr, nullptr);
        ln_kernel<<<4608, 256, 0, stream>>>(tok, h, ln2_g + l*768, ln2_b + l*768);
        zero_counts<<<1, 64, 0, stream>>>(counts);
        gate_kernel<<<4608, 256, 0, stream>>>(h, gate_w + l*3072, gate_b + l*4, wgt, lists, counts);
        gemm_mfma<<<dim3(24,36,4), 256, 0, stream>>>(h, w1 + (size_t)l*4*3072*768, b1 + (size_t)l*4*3072,
                                                     hid, 4608, 3072, 768, 768, 3072, 2,
                                                     lists, counts, nullptr);
        gemm_mfma<<<dim3(6,36,4), 256, 0, stream>>>(hid, w2 + (size_t)l*4*768*3072, b2 + (size_t)l*4*768,
                                                    tok, 4608, 768, 3072, 3072, 768, 3,
                                                    lists, counts, wgt);
    }
    out_transpose<<<13824, 256, 0, stream>>>(tok, out);
}